// Round 3
// baseline (6056.634 us; speedup 1.0000x reference)
//
#include <hip/hip_runtime.h>
#include <hip/hip_bf16.h>

#define HH 256
#define WW 256
#define NB 16
#define CC 64
#define NL 256
#define HWSZ (HH*WW)
#define EPSV 1e-5f

using bf16 = __hip_bfloat16;

__device__ __forceinline__ float to_f(float v){ return v; }
__device__ __forceinline__ float to_f(bf16 v){ return __bfloat162float(v); }
__device__ __forceinline__ void st_f(float* p, float v){ *p = v; }
__device__ __forceinline__ void st_f(bf16*  p, float v){ *p = __float2bfloat16(v); }

// ---------------------------------------------------------------------------
// Fused 3x3 conv (+optional accumulate of previous raw output, +optional
// spatially-constant msg term, +optional BN+ReLU).
// Tile: 32x32 spatial, 8 output channels per block, 2x2 pixels per thread.
// ---------------------------------------------------------------------------
template<typename TIN, typename TOUT>
__global__ __launch_bounds__(256) void conv3x3_k(
    const TIN* __restrict__ in, int Cin,
    const float* __restrict__ wgt, int wCinTot, int wCoff,
    TOUT* __restrict__ out, int Cout,
    const float* __restrict__ bias,
    const float* __restrict__ gamma, const float* __restrict__ beta,
    const float* __restrict__ mean, const float* __restrict__ var,
    const float* __restrict__ msgT, int addPrev)
{
    const int TCI = 4;
    __shared__ float s_in[TCI][34][36];
    __shared__ float s_w[TCI*9*8];

    int tw0 = blockIdx.x * 32;
    int th0 = blockIdx.y * 32;
    int cog = blockIdx.z % (Cout/8);
    int b   = blockIdx.z / (Cout/8);   // chunk-local batch index
    int co0 = cog*8;

    int tid = threadIdx.x;
    int tx = tid & 15, ty = tid >> 4;

    float acc[2][2][8];
    #pragma unroll
    for (int dy=0;dy<2;dy++)
      #pragma unroll
      for (int dx=0;dx<2;dx++)
        #pragma unroll
        for (int co=0;co<8;co++) acc[dy][dx][co]=0.f;

    for (int c0=0;c0<Cin;c0+=TCI) {
        int cnt = min(TCI, Cin-c0);
        __syncthreads();
        // stage input tile (34x34 with halo), zero-padded at image borders
        for (int i = tid; i < cnt*34*34; i += 256) {
            int ci = i / (34*34);
            int rem = i % (34*34);
            int r = rem / 34, cc2 = rem % 34;
            int gy = th0 - 1 + r, gx = tw0 - 1 + cc2;
            float v = 0.f;
            if ((unsigned)gy < HH && (unsigned)gx < WW)
                v = to_f(in[(((size_t)b*Cin + c0+ci)*HH + gy)*WW + gx]);
            s_in[ci][r][cc2] = v;
        }
        // stage weights for this ci-chunk x 8 output channels
        for (int i = tid; i < cnt*9*8; i += 256) {
            int ci = i / 72; int rem = i % 72; int tap = rem / 8; int co = rem % 8;
            s_w[(ci*9+tap)*8+co] =
                wgt[((size_t)(co0+co)*wCinTot + (wCoff + c0 + ci))*9 + tap];
        }
        __syncthreads();
        for (int ci=0; ci<cnt; ci++) {
            float f[4][4];
            #pragma unroll
            for (int r=0;r<4;r++)
                #pragma unroll
                for (int c=0;c<4;c++)
                    f[r][c] = s_in[ci][2*ty+r][2*tx+c];
            #pragma unroll
            for (int p=0;p<3;p++)
              #pragma unroll
              for (int q=0;q<3;q++) {
                float wv[8];
                #pragma unroll
                for (int co=0;co<8;co++) wv[co] = s_w[(ci*9+p*3+q)*8+co];
                #pragma unroll
                for (int dy=0;dy<2;dy++)
                  #pragma unroll
                  for (int dx=0;dx<2;dx++) {
                    float iv = f[p+dy][q+dx];
                    #pragma unroll
                    for (int co=0;co<8;co++) acc[dy][dx][co] += iv*wv[co];
                  }
              }
        }
    }

    // epilogue
    bool bn = (gamma != nullptr);
    float alpha[8], betv[8];
    if (bn) {
      #pragma unroll
      for (int co=0;co<8;co++){
        float g = gamma[co0+co], vv = var[co0+co];
        float m = mean[co0+co], be = beta[co0+co];
        float bi = bias ? bias[co0+co] : 0.f;
        float a = g * rsqrtf(vv + EPSV);
        alpha[co]=a; betv[co]=(bi-m)*a+be;
      }
    }
    #pragma unroll
    for (int dy=0;dy<2;dy++)
      #pragma unroll
      for (int dx=0;dx<2;dx++){
        int h = th0 + 2*ty+dy, w = tw0 + 2*tx+dx;
        #pragma unroll
        for (int co=0;co<8;co++){
            float v = acc[dy][dx][co];
            size_t oidx = (((size_t)b*Cout + co0+co)*HH + h)*WW + w;
            if (addPrev) v += to_f(out[oidx]);
            if (msgT) {
                const float* t = &msgT[((size_t)b*Cout + co0+co)*9];
                float tv = t[0];
                if (h==0)     tv -= t[1];
                if (h==HH-1)  tv -= t[2];
                if (w==0)     tv -= t[3];
                if (w==WW-1)  tv -= t[4];
                if (h==0    && w==0)    tv += t[5];
                if (h==0    && w==WW-1) tv += t[6];
                if (h==HH-1 && w==0)    tv += t[7];
                if (h==HH-1 && w==WW-1) tv += t[8];
                v += tv;
            }
            if (bn) v = fmaxf(alpha[co]*v + betv[co], 0.f);
            st_f(&out[oidx], v);
        }
      }
}

// ---------------------------------------------------------------------------
// Message-channel contribution: T[b,o,comp] — inclusion/exclusion partial
// kernel sums dotted with message. comp: 0=all,1=row0,2=row2,3=col0,4=col2,
// 5..8 = corners (0,0),(0,2),(2,0),(2,2).  Computed for ALL NB batches.
// ---------------------------------------------------------------------------
__global__ __launch_bounds__(256) void msgterm_k(const float* __restrict__ msg,
                                                 const float* __restrict__ wa,
                                                 float* __restrict__ Tbuf)
{
    __shared__ float red[256];
    int b = blockIdx.x, o = blockIdx.y;
    int l = threadIdx.x;
    float m = msg[b*NL + l];
    float wv[9];
    #pragma unroll
    for (int t=0;t<9;t++) wv[t] = wa[((size_t)o*323 + l)*9 + t] * m;
    float comp[9];
    comp[0] = wv[0]+wv[1]+wv[2]+wv[3]+wv[4]+wv[5]+wv[6]+wv[7]+wv[8];
    comp[1] = wv[0]+wv[1]+wv[2];
    comp[2] = wv[6]+wv[7]+wv[8];
    comp[3] = wv[0]+wv[3]+wv[6];
    comp[4] = wv[2]+wv[5]+wv[8];
    comp[5] = wv[0]; comp[6]=wv[2]; comp[7]=wv[6]; comp[8]=wv[8];
    for (int cpi=0;cpi<9;cpi++){
        red[l] = comp[cpi];
        __syncthreads();
        for (int s=128;s>0;s>>=1){ if (l<s) red[l]+=red[l+s]; __syncthreads(); }
        if (l==0) Tbuf[((size_t)b*CC+o)*9+cpi] = red[0];
        __syncthreads();
    }
}

// watermark index list (all indices land in channel 0 since disc(r=10) has
// 317 >= 256 points)
__global__ void build_idx_k(int* __restrict__ idx)
{
    if (threadIdx.x==0 && blockIdx.x==0) {
        int n=0;
        for (int i=-10;i<=10;i++)
            for (int j=-10;j<=10;j++) {
                if (n>=NL) return;
                if (i*i+j*j<=100) { idx[2*n]=128+i; idx[2*n+1]=128+j; n++; }
            }
    }
}

// direct DFT of x[:,0] at the 256 watermark frequencies; D = (m+im) - F0
template<typename TBUF>
__global__ __launch_bounds__(256) void dft_k(const TBUF* __restrict__ x0base,
                                             const float* __restrict__ msg,
                                             const int* __restrict__ idx,
                                             float* __restrict__ D)
{
    __shared__ float twc[256], tws[256];
    __shared__ float red[256];
    int k = blockIdx.x, b = blockIdx.y;   // chunk-local batch
    int h = threadIdx.x;
    float sv, cv;
    __sincosf(6.283185307179586f * (float)h / 256.0f, &sv, &cv);
    twc[h]=cv; tws[h]=sv;
    __syncthreads();
    int yk = idx[2*k], xk = idx[2*k+1];
    const TBUF* row = &x0base[(size_t)b*CC*HWSZ + (size_t)h*WW];
    int m = (yk*h) & 255;
    float fr=0.f, fi=0.f;
    for (int w=0; w<WW; w++) {
        float xv = to_f(row[w]);
        fr += xv*twc[m];
        fi -= xv*tws[m];
        m = (m + xk) & 255;
    }
    red[h]=fr; __syncthreads();
    for (int s=128;s>0;s>>=1){ if(h<s) red[h]+=red[h+s]; __syncthreads(); }
    float FR = red[0]; __syncthreads();
    red[h]=fi; __syncthreads();
    for (int s=128;s>0;s>>=1){ if(h<s) red[h]+=red[h+s]; __syncthreads(); }
    if (h==0) {
        float FI = red[0];
        float mv = msg[b*NL + k];
        D[((size_t)b*NL + k)*2 + 0] = mv - FR;
        D[((size_t)b*NL + k)*2 + 1] = mv - FI;
    }
}

// sparse inverse: x0 += (1/65536) * sum_k Re(D_k * e^{+2pi i (yk h + xk w)/256})
template<typename TBUF>
__global__ __launch_bounds__(256) void delta_k(TBUF* __restrict__ x0base,
                                               const int* __restrict__ idx,
                                               const float* __restrict__ D)
{
    __shared__ float twc[256], tws[256];
    __shared__ float dr[256], di[256];
    __shared__ int iy[256], ix[256];
    int h = blockIdx.x, b = blockIdx.y;   // chunk-local batch
    int w = threadIdx.x;
    float sv, cv;
    __sincosf(6.283185307179586f * (float)w / 256.0f, &sv, &cv);
    twc[w]=cv; tws[w]=sv;
    dr[w] = D[((size_t)b*NL + w)*2+0];
    di[w] = D[((size_t)b*NL + w)*2+1];
    iy[w] = idx[2*w]; ix[w] = idx[2*w+1];
    __syncthreads();
    float acc = 0.f;
    for (int k=0;k<NL;k++) {
        int m = (iy[k]*h + ix[k]*w) & 255;
        acc += dr[k]*twc[m] - di[k]*tws[m];
    }
    TBUF* p = &x0base[(size_t)b*CC*HWSZ + (size_t)h*WW + w];
    st_f(p, to_f(*p) + acc * (1.0f/65536.0f));
}

// final 1x1: out[b,o,hw] = sum_c y[b,c,hw]*wf[o,c] + bf[o]
template<typename TBUF>
__global__ __launch_bounds__(256) void final_k(const TBUF* __restrict__ y,
                                               const float* __restrict__ wf,
                                               const float* __restrict__ bfv,
                                               float* __restrict__ out)
{
    __shared__ float swf[3][64];
    int tid = threadIdx.x;
    if (tid < 192) swf[tid/64][tid%64] = wf[tid];
    __syncthreads();
    size_t pix = (size_t)blockIdx.x*256 + tid;
    size_t b = pix / HWSZ, hw = pix % HWSZ;   // chunk-local batch
    float a0=bfv[0], a1=bfv[1], a2=bfv[2];
    const TBUF* yb = &y[(size_t)b*CC*HWSZ + hw];
    for (int c=0;c<CC;c++){
        float v = to_f(yb[(size_t)c*HWSZ]);
        a0 += v*swf[0][c]; a1 += v*swf[1][c]; a2 += v*swf[2][c];
    }
    float* ob = &out[(size_t)b*3*HWSZ + hw];
    ob[0]              = a0;
    ob[HWSZ]           = a1;
    ob[2*(size_t)HWSZ] = a2;
}

// ---------------------------------------------------------------------------
// Host-side pipeline, templated on intermediate-buffer dtype, batch-chunked
// so the workspace footprint fits ws_size.
// ---------------------------------------------------------------------------
template<typename TBUF>
static void run_pipeline(void* const* d_in, float* out, void* d_ws, int chunk,
                         hipStream_t stream)
{
    const float* image = (const float*)d_in[0];
    const float* msg   = (const float*)d_in[1];
    const float* w0    = (const float*)d_in[2];
    const float* b0    = (const float*)d_in[3];
    const float* g0    = (const float*)d_in[4];
    const float* be0   = (const float*)d_in[5];
    const float* m0    = (const float*)d_in[6];
    const float* v0    = (const float*)d_in[7];
    const float* wk    = (const float*)d_in[8];
    const float* bk    = (const float*)d_in[9];
    const float* gk    = (const float*)d_in[10];
    const float* bek   = (const float*)d_in[11];
    const float* mk    = (const float*)d_in[12];
    const float* vk    = (const float*)d_in[13];
    const float* wa    = (const float*)d_in[14];
    const float* ba    = (const float*)d_in[15];
    const float* ga    = (const float*)d_in[16];
    const float* bea   = (const float*)d_in[17];
    const float* ma    = (const float*)d_in[18];
    const float* va    = (const float*)d_in[19];
    const float* wf    = (const float*)d_in[20];
    const float* bfv   = (const float*)d_in[21];

    // header (128 KB): idx | Dbuf | Tbuf
    char* base = (char*)d_ws;
    int*   idx  = (int*)base;                          // 2*NL ints
    float* Dbuf = (float*)(base + 4096);               // NB*NL*2 floats max
    float* Tbuf = (float*)(base + 4096 + 65536);       // NB*CC*9 floats
    TBUF* bufA = (TBUF*)(base + (1<<17));
    TBUF* bufB = bufA + (size_t)chunk*CC*HWSZ;

    build_idx_k<<<1,64,0,stream>>>(idx);
    msgterm_k<<<dim3(NB,CC),256,0,stream>>>(msg, wa, Tbuf);

    for (int cs = 0; cs < NB; cs += chunk) {
        dim3 cgrid(WW/32, HH/32, chunk*(CC/8));
        const float* img_c = image + (size_t)cs*3*HWSZ;

        // conv0: image -> bufA (BN+ReLU)
        conv3x3_k<float,TBUF><<<cgrid,256,0,stream>>>(img_c, 3, w0, 3, 0, bufA, CC,
            b0, g0, be0, m0, v0, nullptr, 0);
        // conv stack: A->B->A->B
        conv3x3_k<TBUF,TBUF><<<cgrid,256,0,stream>>>(bufA, CC, wk + (size_t)0*CC*CC*9, CC, 0,
            bufB, CC, bk+0*CC, gk+0*CC, bek+0*CC, mk+0*CC, vk+0*CC, nullptr, 0);
        conv3x3_k<TBUF,TBUF><<<cgrid,256,0,stream>>>(bufB, CC, wk + (size_t)1*CC*CC*9, CC, 0,
            bufA, CC, bk+1*CC, gk+1*CC, bek+1*CC, mk+1*CC, vk+1*CC, nullptr, 0);
        conv3x3_k<TBUF,TBUF><<<cgrid,256,0,stream>>>(bufA, CC, wk + (size_t)2*CC*CC*9, CC, 0,
            bufB, CC, bk+2*CC, gk+2*CC, bek+2*CC, mk+2*CC, vk+2*CC, nullptr, 0);

        // watermark in frequency domain (channel 0 only)
        dft_k<TBUF><<<dim3(NL,chunk),256,0,stream>>>(bufB, msg + (size_t)cs*NL, idx, Dbuf);
        delta_k<TBUF><<<dim3(HH,chunk),256,0,stream>>>(bufB, idx, Dbuf);

        // conva pass 1: enc channels (weights offset 256), raw conv -> bufA
        conv3x3_k<TBUF,TBUF><<<cgrid,256,0,stream>>>(bufB, CC, wa, 323, 256, bufA, CC,
            nullptr, nullptr, nullptr, nullptr, nullptr, nullptr, 0);
        // conva pass 2: image channels (offset 320) + prev + msg term, BN+ReLU
        conv3x3_k<float,TBUF><<<cgrid,256,0,stream>>>(img_c, 3, wa, 323, 320, bufA, CC,
            ba, ga, bea, ma, va, Tbuf + (size_t)cs*CC*9, 1);

        // final 1x1 projection -> out (fp32)
        final_k<TBUF><<<(chunk*HWSZ)/256,256,0,stream>>>(bufA, wf, bfv,
            out + (size_t)cs*3*HWSZ);
    }
}

extern "C" void kernel_launch(void* const* d_in, const int* in_sizes, int n_in,
                              void* d_out, int out_size, void* d_ws, size_t ws_size,
                              hipStream_t stream)
{
    float* out = (float*)d_out;
    const size_t HDR = (size_t)1 << 17;          // 128 KB header
    const size_t perB_f32 = (size_t)CC*HWSZ*4;   // 16 MiB per batch per buffer
    const size_t perB_b16 = (size_t)CC*HWSZ*2;

    int chunk_f32 = 0, chunk_b16 = 0;
    for (int c = NB; c >= 1; c >>= 1)
        if (HDR + 2*(size_t)c*perB_f32 <= ws_size) { chunk_f32 = c; break; }
    for (int c = NB; c >= 1; c >>= 1)
        if (HDR + 2*(size_t)c*perB_b16 <= ws_size) { chunk_b16 = c; break; }

    if (chunk_f32 > 0)
        run_pipeline<float>(d_in, out, d_ws, chunk_f32, stream);
    else
        run_pipeline<bf16>(d_in, out, d_ws, chunk_b16 > 0 ? chunk_b16 : 1, stream);
}

// Round 5
// 1561.594 us; speedup vs baseline: 3.8785x; 3.8785x over previous
//
#include <hip/hip_runtime.h>
#include <hip/hip_bf16.h>

#define HH 256
#define WW 256
#define NB 16
#define CC 64
#define NL 256
#define HWSZ (HH*WW)
#define EPSV 1e-5f
#define CAST 104   // conva LDS/weight channel stride

using bf16 = __hip_bfloat16;
using short8  = __attribute__((ext_vector_type(8))) short;
using floatx4 = __attribute__((ext_vector_type(4))) float;

__device__ __forceinline__ ushort f2b(float f){
    bf16 h = __float2bfloat16(f);
    union { bf16 h; ushort u; } cv; cv.h = h; return cv.u;
}
__device__ __forceinline__ float b2fu(ushort u){
    union { unsigned int i; float f; } cv; cv.i = ((unsigned int)u) << 16; return cv.f;
}

// ---------------------------------------------------------------------------
// Weight prep: fp32 OIHW -> bf16 MFMA layouts.
// wkb: [3][9][64][72] (ci 64..71 zero); wab: [9][64][104]
//   (ci 0..63 = wa c=256+ci, 64..66 = wa c=320+.., 67..103 = 0)
// ---------------------------------------------------------------------------
__global__ void prep_w_k(const float* __restrict__ wk, const float* __restrict__ wa,
                         ushort* __restrict__ wkb, ushort* __restrict__ wab)
{
    int i = blockIdx.x*256 + threadIdx.x;
    const int NWK = 3*9*64*72, NWA = 9*64*CAST;
    if (i < NWK) {
        int ci = i % 72; int r = i / 72; int co = r % 64; r /= 64; int tap = r % 9; int t = r / 9;
        float v = (ci < 64) ? wk[(((size_t)t*64 + co)*64 + ci)*9 + tap] : 0.f;
        wkb[i] = f2b(v);
    } else if (i < NWK + NWA) {
        int i2 = i - NWK;
        int ci = i2 % CAST; int r = i2 / CAST; int co = r % 64; int tap = r / 64;
        float v = 0.f;
        if (ci < 64)      v = wa[((size_t)co*323 + 256 + ci)*9 + tap];
        else if (ci < 67) v = wa[((size_t)co*323 + 320 + (ci-64))*9 + tap];
        wab[i2] = f2b(v);
    }
}

// ---------------------------------------------------------------------------
// conv0: fp32 NCHW image (3ch) -> bf16 NHWC (64ch), BN+ReLU. Direct conv.
// ---------------------------------------------------------------------------
__global__ __launch_bounds__(256) void conv0_k(
    const float* __restrict__ img, const float* __restrict__ w0,
    const float* __restrict__ bias, const float* __restrict__ gamma,
    const float* __restrict__ beta, const float* __restrict__ mean,
    const float* __restrict__ var, ushort* __restrict__ outp)
{
    __shared__ float s_i[3][18][18];
    __shared__ float s_wv[64*27];
    __shared__ float s_al[64], s_be[64];
    __shared__ ushort __align__(16) s_y[256*72];

    int tid = threadIdx.x;
    int x0 = blockIdx.x*16, y0 = blockIdx.y*16, b = blockIdx.z;
    if (tid < 64) {
        float a = gamma[tid]*rsqrtf(var[tid]+EPSV);
        s_al[tid] = a; s_be[tid] = (bias[tid]-mean[tid])*a + beta[tid];
    }
    for (int c = tid; c < 64*27; c += 256) s_wv[c] = w0[c];
    for (int c = tid; c < 3*18*18; c += 256) {
        int ci = c / 324, pp = c % 324, py = pp/18, px = pp%18;
        int gy = y0-1+py, gx = x0-1+px;
        float v = 0.f;
        if ((unsigned)gy < 256u && (unsigned)gx < 256u)
            v = img[((size_t)b*3 + ci)*HWSZ + gy*256 + gx];
        s_i[ci][py][px] = v;
    }
    __syncthreads();

    int ly = tid >> 4, lx = tid & 15;
    float xv[27];
    #pragma unroll
    for (int ci=0;ci<3;ci++)
      #pragma unroll
      for (int p=0;p<3;p++)
        #pragma unroll
        for (int q=0;q<3;q++)
            xv[ci*9+p*3+q] = s_i[ci][ly+p][lx+q];

    for (int co=0; co<64; co++) {
        float a = 0.f;
        #pragma unroll
        for (int j=0;j<27;j++) a += xv[j]*s_wv[co*27+j];
        s_y[tid*72 + co] = f2b(fmaxf(s_al[co]*a + s_be[co], 0.f));
    }
    __syncthreads();
    size_t obase = (size_t)b*HWSZ*64;
    for (int c = tid; c < 256*8; c += 256) {
        int ci8 = c & 7, px = c >> 3;
        int gy = y0 + (px>>4), gx = x0 + (px&15);
        *(uint4*)&outp[obase + (size_t)(gy*256+gx)*64 + ci8*8] =
            *(const uint4*)&s_y[px*72 + ci8*8];
    }
}

// ---------------------------------------------------------------------------
// Mid conv 64->64 via MFMA, BN+ReLU, NHWC bf16 -> NHWC bf16.
// Optional fp32 channel-0 plane write (for the DFT stage).
// K chunks {0,32}: all LDS reads stay within the 72-short row (max idx 64+24+8=96?
// no: 32+24+8 = 64 <= 72).
// ---------------------------------------------------------------------------
__global__ __launch_bounds__(256,2) void convm_k(
    const ushort* __restrict__ in, const ushort* __restrict__ wgt, // [9][64][72]
    ushort* __restrict__ outp,
    const float* __restrict__ gamma, const float* __restrict__ beta,
    const float* __restrict__ mean,  const float* __restrict__ var,
    const float* __restrict__ bias,  float* __restrict__ plane)
{
    __shared__ ushort __align__(16) s_x[18*18*72];
    __shared__ ushort __align__(16) s_w[2][64*72];
    __shared__ float s_al[64], s_be[64];

    const int tid = threadIdx.x;
    const int x0 = blockIdx.x*16, y0 = blockIdx.y*16, b = blockIdx.z;

    if (tid < 64) {
        float a = gamma[tid]*rsqrtf(var[tid]+EPSV);
        s_al[tid] = a; s_be[tid] = (bias[tid]-mean[tid])*a + beta[tid];
    }
    const size_t ibase = (size_t)b*HWSZ*64;
    for (int c = tid; c < 18*18*8; c += 256) {
        int ci8 = c & 7, pp = c >> 3;
        int px = pp % 18, py = pp / 18;
        int gy = y0-1+py, gx = x0-1+px;
        uint4 v = make_uint4(0,0,0,0);
        if ((unsigned)gy < 256u && (unsigned)gx < 256u)
            v = *(const uint4*)&in[ibase + (size_t)(gy*256+gx)*64 + ci8*8];
        *(uint4*)&s_x[(py*18+px)*72 + ci8*8] = v;
    }
    for (int c = tid; c < 64*9; c += 256) {
        int ci8 = c % 9, co = c / 9;
        *(uint4*)&s_w[0][co*72 + ci8*8] = *(const uint4*)&wgt[(size_t)co*72 + ci8*8];
    }
    __syncthreads();

    const int lane = tid & 63, wid = tid >> 6;
    const int n16 = lane & 15, quad = lane >> 4;

    floatx4 acc[4][4];
    #pragma unroll
    for (int mi=0;mi<4;mi++)
      #pragma unroll
      for (int ni=0;ni<4;ni++)
        #pragma unroll
        for (int r=0;r<4;r++) acc[mi][ni][r] = 0.f;

    for (int tap=0; tap<9; ++tap) {
        int cur = tap & 1;
        if (tap < 8) {
            const ushort* wsrc = &wgt[(size_t)(tap+1)*64*72];
            for (int c = tid; c < 64*9; c += 256) {
                int ci8 = c % 9, co = c / 9;
                *(uint4*)&s_w[cur^1][co*72 + ci8*8] = *(const uint4*)&wsrc[co*72 + ci8*8];
            }
        }
        int p = tap/3, q = tap%3;
        #pragma unroll
        for (int kc=0; kc<64; kc+=32) {
            short8 af[4], bfr[4];
            #pragma unroll
            for (int mi=0;mi<4;mi++)
                af[mi] = *(const short8*)&s_w[cur][(mi*16+n16)*72 + kc + quad*8];
            #pragma unroll
            for (int ni=0;ni<4;ni++) {
                int yy = wid*4 + ni + p, xx = n16 + q;
                bfr[ni] = *(const short8*)&s_x[(yy*18+xx)*72 + kc + quad*8];
            }
            #pragma unroll
            for (int mi=0;mi<4;mi++)
              #pragma unroll
              for (int ni=0;ni<4;ni++)
                acc[mi][ni] = __builtin_amdgcn_mfma_f32_16x16x32_bf16(
                    af[mi], bfr[ni], acc[mi][ni], 0, 0, 0);
        }
        __syncthreads();
    }

    // epilogue: BN+ReLU -> s_y (reuse s_x), then coalesced NHWC store
    ushort* s_y = s_x;
    #pragma unroll
    for (int mi=0;mi<4;mi++)
      #pragma unroll
      for (int ni=0;ni<4;ni++) {
        int px = (wid*4+ni)*16 + n16;
        int cob = mi*16 + quad*4;
        ushort u[4];
        #pragma unroll
        for (int r=0;r<4;r++) {
            float y = fmaxf(s_al[cob+r]*acc[mi][ni][r] + s_be[cob+r], 0.f);
            u[r] = f2b(y);
            if (plane && mi==0 && quad==0 && r==0)
                plane[(size_t)b*HWSZ + (y0+wid*4+ni)*256 + x0 + n16] = y;
        }
        uint2 pk; pk.x = (uint)u[0] | ((uint)u[1]<<16); pk.y = (uint)u[2] | ((uint)u[3]<<16);
        *(uint2*)&s_y[px*72 + cob] = pk;
      }
    __syncthreads();
    for (int c = tid; c < 256*8; c += 256) {
        int ci8 = c & 7, px = c >> 3;
        int gy = y0 + (px>>4), gx = x0 + (px&15);
        *(uint4*)&outp[ibase + (size_t)(gy*256+gx)*64 + ci8*8] =
            *(const uint4*)&s_y[px*72 + ci8*8];
    }
}

// ---------------------------------------------------------------------------
// conva fused: MFMA conv over 67 real channels (64 enc + 3 image), stride-104
// padded K (chunks {0,32,64}, ci 67..95 zero, 96..103 never read).
// Watermark delta folded into staging; epilogue = msgT + BN + ReLU + 1x1
// projection + cross-quad reduce -> fp32 NCHW output.
// ---------------------------------------------------------------------------
__global__ __launch_bounds__(256,1) void conva_k(
    const ushort* __restrict__ enc, const float* __restrict__ img,
    const float* __restrict__ dplane, const ushort* __restrict__ wgt, // [9][64][104]
    const float* __restrict__ gamma, const float* __restrict__ beta,
    const float* __restrict__ mean,  const float* __restrict__ var,
    const float* __restrict__ bias,
    const float* __restrict__ Tb,    // [b][64][9]
    const float* __restrict__ wf, const float* __restrict__ bfv,
    float* __restrict__ outp)
{
    __shared__ ushort __align__(16) s_x[18*18*CAST];
    __shared__ ushort __align__(16) s_w[2][64*CAST];
    __shared__ float s_al[64], s_be[64];
    __shared__ float s_T[64*9];
    __shared__ float s_wf[3*64];
    __shared__ float s_bf[3];

    const int tid = threadIdx.x;
    const int x0 = blockIdx.x*16, y0 = blockIdx.y*16, b = blockIdx.z;

    if (tid < 64) {
        float a = gamma[tid]*rsqrtf(var[tid]+EPSV);
        s_al[tid] = a; s_be[tid] = (bias[tid]-mean[tid])*a + beta[tid];
    }
    if (tid < 192) s_wf[tid] = wf[tid];
    if (tid < 3)   s_bf[tid] = bfv[tid];
    for (int c = tid; c < 64*9; c += 256) s_T[c] = Tb[(size_t)b*576 + c];

    const size_t ibase = (size_t)b*HWSZ*64;
    for (int c = tid; c < 18*18*13; c += 256) {
        int ci8 = c % 13, pp = c / 13;
        int px = pp % 18, py = pp / 18;
        int gy = y0-1+py, gx = x0-1+px;
        bool ok = (unsigned)gy < 256u && (unsigned)gx < 256u;
        uint4 v = make_uint4(0,0,0,0);
        if (ci8 < 8) {
            if (ok) {
                v = *(const uint4*)&enc[ibase + (size_t)(gy*256+gx)*64 + ci8*8];
                if (ci8 == 0) {
                    float d = dplane[(size_t)b*HWSZ + gy*256 + gx];
                    ushort nb = f2b(b2fu((ushort)(v.x & 0xffffu)) + d);
                    v.x = (v.x & 0xffff0000u) | (uint)nb;
                }
            }
        } else if (ci8 == 8 && ok) {
            float i0 = img[((size_t)b*3 + 0)*HWSZ + gy*256 + gx];
            float i1 = img[((size_t)b*3 + 1)*HWSZ + gy*256 + gx];
            float i2 = img[((size_t)b*3 + 2)*HWSZ + gy*256 + gx];
            v.x = (uint)f2b(i0) | ((uint)f2b(i1) << 16);
            v.y = (uint)f2b(i2);
        }
        *(uint4*)&s_x[(py*18+px)*CAST + ci8*8] = v;
    }
    for (int c = tid; c < 64*13; c += 256) {
        int ci8 = c % 13, co = c / 13;
        *(uint4*)&s_w[0][co*CAST + ci8*8] = *(const uint4*)&wgt[(size_t)co*CAST + ci8*8];
    }
    __syncthreads();

    const int lane = tid & 63, wid = tid >> 6;
    const int n16 = lane & 15, quad = lane >> 4;

    floatx4 acc[4][4];
    #pragma unroll
    for (int mi=0;mi<4;mi++)
      #pragma unroll
      for (int ni=0;ni<4;ni++)
        #pragma unroll
        for (int r=0;r<4;r++) acc[mi][ni][r] = 0.f;

    for (int tap=0; tap<9; ++tap) {
        int cur = tap & 1;
        if (tap < 8) {
            const ushort* wsrc = &wgt[(size_t)(tap+1)*64*CAST];
            for (int c = tid; c < 64*13; c += 256) {
                int ci8 = c % 13, co = c / 13;
                *(uint4*)&s_w[cur^1][co*CAST + ci8*8] = *(const uint4*)&wsrc[co*CAST + ci8*8];
            }
        }
        int p = tap/3, q = tap%3;
        #pragma unroll
        for (int kc=0; kc<96; kc+=32) {
            short8 af[4], bfr[4];
            #pragma unroll
            for (int mi=0;mi<4;mi++)
                af[mi] = *(const short8*)&s_w[cur][(mi*16+n16)*CAST + kc + quad*8];
            #pragma unroll
            for (int ni=0;ni<4;ni++) {
                int yy = wid*4 + ni + p, xx = n16 + q;
                bfr[ni] = *(const short8*)&s_x[(yy*18+xx)*CAST + kc + quad*8];
            }
            #pragma unroll
            for (int mi=0;mi<4;mi++)
              #pragma unroll
              for (int ni=0;ni<4;ni++)
                acc[mi][ni] = __builtin_amdgcn_mfma_f32_16x16x32_bf16(
                    af[mi], bfr[ni], acc[mi][ni], 0, 0, 0);
        }
        __syncthreads();
    }

    // epilogue: msgT + BN + ReLU + 1x1 projection + cross-quad reduce
    float po[3][4];
    #pragma unroll
    for (int o=0;o<3;o++)
      #pragma unroll
      for (int ni=0;ni<4;ni++) po[o][ni] = 0.f;

    #pragma unroll
    for (int mi=0;mi<4;mi++) {
        int cob = mi*16 + quad*4;
        #pragma unroll
        for (int r=0;r<4;r++) {
            int co = cob + r;
            float al = s_al[co], be = s_be[co];
            const float* t = &s_T[co*9];
            float w0f = s_wf[0*64+co], w1f = s_wf[1*64+co], w2f = s_wf[2*64+co];
            #pragma unroll
            for (int ni=0;ni<4;ni++) {
                int h = y0 + wid*4 + ni, w = x0 + n16;
                float tv = t[0];
                if (h==0)   tv -= t[1];
                if (h==255) tv -= t[2];
                if (w==0)   tv -= t[3];
                if (w==255) tv -= t[4];
                if (h==0   && w==0)   tv += t[5];
                if (h==0   && w==255) tv += t[6];
                if (h==255 && w==0)   tv += t[7];
                if (h==255 && w==255) tv += t[8];
                float y = fmaxf(al*(acc[mi][ni][r] + tv) + be, 0.f);
                po[0][ni] += w0f*y; po[1][ni] += w1f*y; po[2][ni] += w2f*y;
            }
        }
    }
    #pragma unroll
    for (int o=0;o<3;o++)
      #pragma unroll
      for (int ni=0;ni<4;ni++) {
        float pv = po[o][ni];
        pv += __shfl_xor(pv, 16, 64);
        pv += __shfl_xor(pv, 32, 64);
        if (quad == o) {
            int h = y0 + wid*4 + ni, w = x0 + n16;
            outp[((size_t)b*3 + o)*HWSZ + h*256 + w] = pv + s_bf[o];
        }
      }
}

// ---------------------------------------------------------------------------
// msgterm / idx / dft / delta
// ---------------------------------------------------------------------------
__global__ __launch_bounds__(256) void msgterm_k(const float* __restrict__ msg,
                                                 const float* __restrict__ wa,
                                                 float* __restrict__ Tbuf)
{
    __shared__ float red[256];
    int b = blockIdx.x, o = blockIdx.y, l = threadIdx.x;
    float m = msg[b*NL + l];
    float wv[9];
    #pragma unroll
    for (int t=0;t<9;t++) wv[t] = wa[((size_t)o*323 + l)*9 + t] * m;
    float comp[9];
    comp[0] = wv[0]+wv[1]+wv[2]+wv[3]+wv[4]+wv[5]+wv[6]+wv[7]+wv[8];
    comp[1] = wv[0]+wv[1]+wv[2];
    comp[2] = wv[6]+wv[7]+wv[8];
    comp[3] = wv[0]+wv[3]+wv[6];
    comp[4] = wv[2]+wv[5]+wv[8];
    comp[5] = wv[0]; comp[6]=wv[2]; comp[7]=wv[6]; comp[8]=wv[8];
    for (int cpi=0;cpi<9;cpi++){
        red[l] = comp[cpi];
        __syncthreads();
        for (int s=128;s>0;s>>=1){ if (l<s) red[l]+=red[l+s]; __syncthreads(); }
        if (l==0) Tbuf[((size_t)b*CC+o)*9+cpi] = red[0];
        __syncthreads();
    }
}

__global__ void build_idx_k(int* __restrict__ idx)
{
    if (threadIdx.x==0 && blockIdx.x==0) {
        int n=0;
        for (int i=-10;i<=10;i++)
            for (int j=-10;j<=10;j++) {
                if (n>=NL) return;
                if (i*i+j*j<=100) { idx[2*n]=128+i; idx[2*n+1]=128+j; n++; }
            }
    }
}

__global__ __launch_bounds__(256) void dft_k(const float* __restrict__ plane,
                                             const float* __restrict__ msg,
                                             const int* __restrict__ idx,
                                             float* __restrict__ D)
{
    __shared__ float twc[256], tws[256], red[256];
    int k = blockIdx.x, b = blockIdx.y, w = threadIdx.x;
    float sv, cv;
    __sincosf(6.283185307179586f * (float)w / 256.0f, &sv, &cv);
    twc[w]=cv; tws[w]=sv;
    __syncthreads();
    int yk = idx[2*k], xk = idx[2*k+1];
    const float* pb = &plane[(size_t)b*HWSZ];
    int m = (xk*w) & 255;
    float fr=0.f, fi=0.f;
    for (int h=0; h<256; h++) {
        float xv = pb[h*256 + w];
        fr += xv*twc[m];
        fi -= xv*tws[m];
        m = (m + yk) & 255;
    }
    red[w]=fr; __syncthreads();
    for (int s=128;s>0;s>>=1){ if(w<s) red[w]+=red[w+s]; __syncthreads(); }
    float FR = red[0]; __syncthreads();
    red[w]=fi; __syncthreads();
    for (int s=128;s>0;s>>=1){ if(w<s) red[w]+=red[w+s]; __syncthreads(); }
    if (w==0) {
        float FI = red[0];
        float mv = msg[b*NL + k];
        D[((size_t)b*NL + k)*2 + 0] = mv - FR;
        D[((size_t)b*NL + k)*2 + 1] = mv - FI;
    }
}

__global__ __launch_bounds__(256) void deltaplane_k(const int* __restrict__ idx,
                                                    const float* __restrict__ D,
                                                    float* __restrict__ dplane)
{
    __shared__ float twc[256], tws[256], dr[256], di[256];
    __shared__ int iy[256], ix[256];
    int h = blockIdx.x, b = blockIdx.y, w = threadIdx.x;
    float sv, cv;
    __sincosf(6.283185307179586f * (float)w / 256.0f, &sv, &cv);
    twc[w]=cv; tws[w]=sv;
    dr[w] = D[((size_t)b*NL + w)*2+0];
    di[w] = D[((size_t)b*NL + w)*2+1];
    iy[w] = idx[2*w]; ix[w] = idx[2*w+1];
    __syncthreads();
    float acc = 0.f;
    for (int k=0;k<NL;k++) {
        int m = (iy[k]*h + ix[k]*w) & 255;
        acc += dr[k]*twc[m] - di[k]*tws[m];
    }
    dplane[(size_t)b*HWSZ + h*256 + w] = acc * (1.0f/65536.0f);
}

// ---------------------------------------------------------------------------
extern "C" void kernel_launch(void* const* d_in, const int* in_sizes, int n_in,
                              void* d_out, int out_size, void* d_ws, size_t ws_size,
                              hipStream_t stream)
{
    const float* image = (const float*)d_in[0];
    const float* msg   = (const float*)d_in[1];
    const float* w0    = (const float*)d_in[2];
    const float* b0    = (const float*)d_in[3];
    const float* g0    = (const float*)d_in[4];
    const float* be0   = (const float*)d_in[5];
    const float* m0    = (const float*)d_in[6];
    const float* v0    = (const float*)d_in[7];
    const float* wk    = (const float*)d_in[8];
    const float* bk    = (const float*)d_in[9];
    const float* gk    = (const float*)d_in[10];
    const float* bek   = (const float*)d_in[11];
    const float* mk    = (const float*)d_in[12];
    const float* vk    = (const float*)d_in[13];
    const float* wa    = (const float*)d_in[14];
    const float* ba    = (const float*)d_in[15];
    const float* ga    = (const float*)d_in[16];
    const float* bea   = (const float*)d_in[17];
    const float* ma    = (const float*)d_in[18];
    const float* va    = (const float*)d_in[19];
    const float* wf    = (const float*)d_in[20];
    const float* bfv   = (const float*)d_in[21];
    float* out = (float*)d_out;

    char* base = (char*)d_ws;
    int*    idx    = (int*)base;                       // 2 KB
    float*  Dbuf   = (float*)(base + (4<<10));         // 32 KB
    float*  Tbuf   = (float*)(base + (64<<10));        // 36 KB
    ushort* wkb    = (ushort*)(base + (128<<10));      // 243 KB
    ushort* wab    = (ushort*)(base + (512<<10));      // 117 KB
    float*  plane  = (float*)(base + ((size_t)1<<20)); // 4 MB
    float*  dplane = (float*)(base + ((size_t)5<<20)); // 4 MB
    ushort* bufA   = (ushort*)(base + ((size_t)16<<20));

    const size_t perB = (size_t)HWSZ*64*2*2;  // 16 MiB: both bf16 buffers / batch
    int chunk = 1;
    for (int c = NB; c >= 1; c >>= 1)
        if (((size_t)16<<20) + (size_t)c*perB <= ws_size) { chunk = c; break; }
    ushort* bufB = bufA + (size_t)chunk*HWSZ*64;

    build_idx_k<<<1,64,0,stream>>>(idx);
    msgterm_k<<<dim3(NB,CC),256,0,stream>>>(msg, wa, Tbuf);
    int prep_n = (3*9*64*72 + 9*64*CAST + 255)/256;
    prep_w_k<<<prep_n,256,0,stream>>>(wk, wa, wkb, wab);

    const size_t WL = (size_t)9*64*72;  // one layer of wkb

    for (int cs = 0; cs < NB; cs += chunk) {
        dim3 g(16,16,chunk);
        const float* img_c = image + (size_t)cs*3*HWSZ;

        conv0_k<<<g,256,0,stream>>>(img_c, w0, b0, g0, be0, m0, v0, bufA);
        convm_k<<<g,256,0,stream>>>(bufA, wkb + 0*WL, bufB,
            gk+0*CC, bek+0*CC, mk+0*CC, vk+0*CC, bk+0*CC, nullptr);
        convm_k<<<g,256,0,stream>>>(bufB, wkb + 1*WL, bufA,
            gk+1*CC, bek+1*CC, mk+1*CC, vk+1*CC, bk+1*CC, nullptr);
        convm_k<<<g,256,0,stream>>>(bufA, wkb + 2*WL, bufB,
            gk+2*CC, bek+2*CC, mk+2*CC, vk+2*CC, bk+2*CC, plane);

        dft_k<<<dim3(NL,chunk),256,0,stream>>>(plane, msg + (size_t)cs*NL, idx, Dbuf);
        deltaplane_k<<<dim3(HH,chunk),256,0,stream>>>(idx, Dbuf, dplane);

        conva_k<<<g,256,0,stream>>>(bufB, img_c, dplane, wab,
            ga, bea, ma, va, ba, Tbuf + (size_t)cs*CC*9, wf, bfv,
            out + (size_t)cs*3*HWSZ);
    }
}

// Round 6
// 1436.998 us; speedup vs baseline: 4.2148x; 1.0867x over previous
//
#include <hip/hip_runtime.h>
#include <hip/hip_bf16.h>

#define HH 256
#define WW 256
#define NB 16
#define CC 64
#define NL 256
#define HWSZ (HH*WW)
#define EPSV 1e-5f
#define CAST 104   // conva LDS channel stride (shorts)

using bf16 = __hip_bfloat16;
using short8  = __attribute__((ext_vector_type(8))) short;
using floatx4 = __attribute__((ext_vector_type(4))) float;

__device__ __forceinline__ ushort f2b(float f){
    bf16 h = __float2bfloat16(f);
    union { bf16 h; ushort u; } cv; cv.h = h; return cv.u;
}
__device__ __forceinline__ float b2fu(ushort u){
    union { unsigned int i; float f; } cv; cv.i = ((unsigned int)u) << 16; return cv.f;
}

// ---------------------------------------------------------------------------
// Weight prep.
// wkb2: [3][9][64][64]  (t, tap, co, ci)   — convm A-frags, read from global
// wab2: [9][64][96]     (tap, co, ci96): ci 0..63 = wa(256+ci), 64..66 =
//        wa(320+..), 67..95 = 0          — conva A-frags
// ---------------------------------------------------------------------------
__global__ void prep_w_k(const float* __restrict__ wk, const float* __restrict__ wa,
                         ushort* __restrict__ wkb2, ushort* __restrict__ wab2)
{
    int i = blockIdx.x*256 + threadIdx.x;
    const int NWK = 3*9*64*64, NWA = 9*64*96;
    if (i < NWK) {
        int ci = i & 63; int r = i >> 6; int co = r & 63; r >>= 6; int tap = r % 9; int t = r / 9;
        wkb2[i] = f2b(wk[(((size_t)t*64 + co)*64 + ci)*9 + tap]);
    } else if (i < NWK + NWA) {
        int i2 = i - NWK;
        int ci = i2 % 96; int r = i2 / 96; int co = r & 63; int tap = r >> 6;
        float v = 0.f;
        if (ci < 64)      v = wa[((size_t)co*323 + 256 + ci)*9 + tap];
        else if (ci < 67) v = wa[((size_t)co*323 + 320 + (ci-64))*9 + tap];
        wab2[i2] = f2b(v);
    }
}

// ---------------------------------------------------------------------------
// conv0: fp32 NCHW image (3ch) -> bf16 NHWC (64ch), BN+ReLU. Direct conv.
// ---------------------------------------------------------------------------
__global__ __launch_bounds__(256) void conv0_k(
    const float* __restrict__ img, const float* __restrict__ w0,
    const float* __restrict__ bias, const float* __restrict__ gamma,
    const float* __restrict__ beta, const float* __restrict__ mean,
    const float* __restrict__ var, ushort* __restrict__ outp)
{
    __shared__ float s_i[3][18][18];
    __shared__ float s_wv[64*27];
    __shared__ float s_al[64], s_be[64];
    __shared__ ushort __align__(16) s_y[256*72];

    int tid = threadIdx.x;
    int x0 = blockIdx.x*16, y0 = blockIdx.y*16, b = blockIdx.z;
    if (tid < 64) {
        float a = gamma[tid]*rsqrtf(var[tid]+EPSV);
        s_al[tid] = a; s_be[tid] = (bias[tid]-mean[tid])*a + beta[tid];
    }
    for (int c = tid; c < 64*27; c += 256) s_wv[c] = w0[c];
    for (int c = tid; c < 3*18*18; c += 256) {
        int ci = c / 324, pp = c % 324, py = pp/18, px = pp%18;
        int gy = y0-1+py, gx = x0-1+px;
        float v = 0.f;
        if ((unsigned)gy < 256u && (unsigned)gx < 256u)
            v = img[((size_t)b*3 + ci)*HWSZ + gy*256 + gx];
        s_i[ci][py][px] = v;
    }
    __syncthreads();

    int ly = tid >> 4, lx = tid & 15;
    float xv[27];
    #pragma unroll
    for (int ci=0;ci<3;ci++)
      #pragma unroll
      for (int p=0;p<3;p++)
        #pragma unroll
        for (int q=0;q<3;q++)
            xv[ci*9+p*3+q] = s_i[ci][ly+p][lx+q];

    for (int co=0; co<64; co++) {
        float a = 0.f;
        #pragma unroll
        for (int j=0;j<27;j++) a += xv[j]*s_wv[co*27+j];
        s_y[tid*72 + co] = f2b(fmaxf(s_al[co]*a + s_be[co], 0.f));
    }
    __syncthreads();
    size_t obase = (size_t)b*HWSZ*64;
    for (int c = tid; c < 256*8; c += 256) {
        int ci8 = c & 7, px = c >> 3;
        int gy = y0 + (px>>4), gx = x0 + (px&15);
        *(uint4*)&outp[obase + (size_t)(gy*256+gx)*64 + ci8*8] =
            *(const uint4*)&s_y[px*72 + ci8*8];
    }
}

// ---------------------------------------------------------------------------
// Mid conv 64->64 via MFMA, barrier-free K-loop:
//   - input tile staged once in LDS (stride 72)
//   - A-frags read straight from global wkb2 [9][64][64] (L1/L2-resident)
//   - B-row fragments reused across tap rows p (6 reads feed 3 p values)
// ---------------------------------------------------------------------------
__global__ __launch_bounds__(256,3) void convm_k(
    const ushort* __restrict__ in, const ushort* __restrict__ wgt, // [9][64][64]
    ushort* __restrict__ outp,
    const float* __restrict__ gamma, const float* __restrict__ beta,
    const float* __restrict__ mean,  const float* __restrict__ var,
    const float* __restrict__ bias,  float* __restrict__ plane)
{
    __shared__ ushort __align__(16) s_x[18*18*72];
    __shared__ float s_al[64], s_be[64];

    const int tid = threadIdx.x;
    const int x0 = blockIdx.x*16, y0 = blockIdx.y*16, b = blockIdx.z;

    if (tid < 64) {
        float a = gamma[tid]*rsqrtf(var[tid]+EPSV);
        s_al[tid] = a; s_be[tid] = (bias[tid]-mean[tid])*a + beta[tid];
    }
    const size_t ibase = (size_t)b*HWSZ*64;
    for (int c = tid; c < 18*18*8; c += 256) {
        int ci8 = c & 7, pp = c >> 3;
        int px = pp % 18, py = pp / 18;
        int gy = y0-1+py, gx = x0-1+px;
        uint4 v = make_uint4(0,0,0,0);
        if ((unsigned)gy < 256u && (unsigned)gx < 256u)
            v = *(const uint4*)&in[ibase + (size_t)(gy*256+gx)*64 + ci8*8];
        *(uint4*)&s_x[(py*18+px)*72 + ci8*8] = v;
    }
    __syncthreads();

    const int lane = tid & 63, wid = tid >> 6;
    const int n16 = lane & 15, quad = lane >> 4;

    floatx4 acc[4][4];
    #pragma unroll
    for (int mi=0;mi<4;mi++)
      #pragma unroll
      for (int ni=0;ni<4;ni++)
        #pragma unroll
        for (int r=0;r<4;r++) acc[mi][ni][r] = 0.f;

    #pragma unroll
    for (int q=0; q<3; q++) {
        #pragma unroll
        for (int kc=0; kc<64; kc+=32) {
            short8 bfr[6];
            #pragma unroll
            for (int rr=0; rr<6; rr++)
                bfr[rr] = *(const short8*)&s_x[((wid*4+rr)*18 + n16+q)*72 + kc + quad*8];
            short8 af[3][4];
            #pragma unroll
            for (int p=0;p<3;p++)
              #pragma unroll
              for (int mi=0;mi<4;mi++)
                af[p][mi] = *(const short8*)&wgt[((size_t)(p*3+q)*64 + mi*16+n16)*64 + kc + quad*8];
            #pragma unroll
            for (int p=0;p<3;p++)
              #pragma unroll
              for (int mi=0;mi<4;mi++)
                #pragma unroll
                for (int ni=0;ni<4;ni++)
                  acc[mi][ni] = __builtin_amdgcn_mfma_f32_16x16x32_bf16(
                      af[p][mi], bfr[ni+p], acc[mi][ni], 0, 0, 0);
        }
    }
    __syncthreads();

    // epilogue: BN+ReLU -> s_y (reuse s_x), then coalesced NHWC store
    ushort* s_y = s_x;
    #pragma unroll
    for (int mi=0;mi<4;mi++)
      #pragma unroll
      for (int ni=0;ni<4;ni++) {
        int px = (wid*4+ni)*16 + n16;
        int cob = mi*16 + quad*4;
        ushort u[4];
        #pragma unroll
        for (int r=0;r<4;r++) {
            float y = fmaxf(s_al[cob+r]*acc[mi][ni][r] + s_be[cob+r], 0.f);
            u[r] = f2b(y);
            if (plane && mi==0 && quad==0 && r==0)
                plane[(size_t)b*HWSZ + (y0+wid*4+ni)*256 + x0 + n16] = y;
        }
        uint2 pk; pk.x = (uint)u[0] | ((uint)u[1]<<16); pk.y = (uint)u[2] | ((uint)u[3]<<16);
        *(uint2*)&s_y[px*72 + cob] = pk;
      }
    __syncthreads();
    for (int c = tid; c < 256*8; c += 256) {
        int ci8 = c & 7, px = c >> 3;
        int gy = y0 + (px>>4), gx = x0 + (px&15);
        *(uint4*)&outp[ibase + (size_t)(gy*256+gx)*64 + ci8*8] =
            *(const uint4*)&s_y[px*72 + ci8*8];
    }
}

// ---------------------------------------------------------------------------
// conva fused: barrier-free MFMA conv over 67 real channels (64 enc + 3 img),
// K chunks {0,32,64} over stride-104 LDS / stride-96 global weights.
// Watermark delta folded into staging; epilogue = msgT + BN + ReLU + 1x1
// projection + cross-quad reduce -> fp32 NCHW output.
// ---------------------------------------------------------------------------
__global__ __launch_bounds__(256,2) void conva_k(
    const ushort* __restrict__ enc, const float* __restrict__ img,
    const float* __restrict__ dplane, const ushort* __restrict__ wgt, // [9][64][96]
    const float* __restrict__ gamma, const float* __restrict__ beta,
    const float* __restrict__ mean,  const float* __restrict__ var,
    const float* __restrict__ bias,
    const float* __restrict__ Tb,    // [b][64][9]
    const float* __restrict__ wf, const float* __restrict__ bfv,
    float* __restrict__ outp)
{
    __shared__ ushort __align__(16) s_x[18*18*CAST];
    __shared__ float s_al[64], s_be[64];
    __shared__ float s_T[64*9];
    __shared__ float s_wf[3*64];
    __shared__ float s_bf[3];

    const int tid = threadIdx.x;
    const int x0 = blockIdx.x*16, y0 = blockIdx.y*16, b = blockIdx.z;

    if (tid < 64) {
        float a = gamma[tid]*rsqrtf(var[tid]+EPSV);
        s_al[tid] = a; s_be[tid] = (bias[tid]-mean[tid])*a + beta[tid];
    }
    if (tid < 192) s_wf[tid] = wf[tid];
    if (tid < 3)   s_bf[tid] = bfv[tid];
    for (int c = tid; c < 64*9; c += 256) s_T[c] = Tb[(size_t)b*576 + c];

    const size_t ibase = (size_t)b*HWSZ*64;
    for (int c = tid; c < 18*18*13; c += 256) {
        int ci8 = c % 13, pp = c / 13;
        int px = pp % 18, py = pp / 18;
        int gy = y0-1+py, gx = x0-1+px;
        bool ok = (unsigned)gy < 256u && (unsigned)gx < 256u;
        uint4 v = make_uint4(0,0,0,0);
        if (ci8 < 8) {
            if (ok) {
                v = *(const uint4*)&enc[ibase + (size_t)(gy*256+gx)*64 + ci8*8];
                if (ci8 == 0) {
                    float d = dplane[(size_t)b*HWSZ + gy*256 + gx];
                    ushort nb = f2b(b2fu((ushort)(v.x & 0xffffu)) + d);
                    v.x = (v.x & 0xffff0000u) | (uint)nb;
                }
            }
        } else if (ci8 == 8 && ok) {
            float i0 = img[((size_t)b*3 + 0)*HWSZ + gy*256 + gx];
            float i1 = img[((size_t)b*3 + 1)*HWSZ + gy*256 + gx];
            float i2 = img[((size_t)b*3 + 2)*HWSZ + gy*256 + gx];
            v.x = (uint)f2b(i0) | ((uint)f2b(i1) << 16);
            v.y = (uint)f2b(i2);
        }
        *(uint4*)&s_x[(py*18+px)*CAST + ci8*8] = v;
    }
    __syncthreads();

    const int lane = tid & 63, wid = tid >> 6;
    const int n16 = lane & 15, quad = lane >> 4;

    floatx4 acc[4][4];
    #pragma unroll
    for (int mi=0;mi<4;mi++)
      #pragma unroll
      for (int ni=0;ni<4;ni++)
        #pragma unroll
        for (int r=0;r<4;r++) acc[mi][ni][r] = 0.f;

    #pragma unroll
    for (int q=0; q<3; q++) {
        #pragma unroll
        for (int kc=0; kc<96; kc+=32) {
            short8 bfr[6];
            #pragma unroll
            for (int rr=0; rr<6; rr++)
                bfr[rr] = *(const short8*)&s_x[((wid*4+rr)*18 + n16+q)*CAST + kc + quad*8];
            short8 af[3][4];
            #pragma unroll
            for (int p=0;p<3;p++)
              #pragma unroll
              for (int mi=0;mi<4;mi++)
                af[p][mi] = *(const short8*)&wgt[((size_t)(p*3+q)*64 + mi*16+n16)*96 + kc + quad*8];
            #pragma unroll
            for (int p=0;p<3;p++)
              #pragma unroll
              for (int mi=0;mi<4;mi++)
                #pragma unroll
                for (int ni=0;ni<4;ni++)
                  acc[mi][ni] = __builtin_amdgcn_mfma_f32_16x16x32_bf16(
                      af[p][mi], bfr[ni+p], acc[mi][ni], 0, 0, 0);
        }
    }

    // epilogue: msgT + BN + ReLU + 1x1 projection + cross-quad reduce
    float po[3][4];
    #pragma unroll
    for (int o=0;o<3;o++)
      #pragma unroll
      for (int ni=0;ni<4;ni++) po[o][ni] = 0.f;

    #pragma unroll
    for (int mi=0;mi<4;mi++) {
        int cob = mi*16 + quad*4;
        #pragma unroll
        for (int r=0;r<4;r++) {
            int co = cob + r;
            float al = s_al[co], be = s_be[co];
            const float* t = &s_T[co*9];
            float w0f = s_wf[0*64+co], w1f = s_wf[1*64+co], w2f = s_wf[2*64+co];
            #pragma unroll
            for (int ni=0;ni<4;ni++) {
                int h = y0 + wid*4 + ni, w = x0 + n16;
                float tv = t[0];
                if (h==0)   tv -= t[1];
                if (h==255) tv -= t[2];
                if (w==0)   tv -= t[3];
                if (w==255) tv -= t[4];
                if (h==0   && w==0)   tv += t[5];
                if (h==0   && w==255) tv += t[6];
                if (h==255 && w==0)   tv += t[7];
                if (h==255 && w==255) tv += t[8];
                float y = fmaxf(al*(acc[mi][ni][r] + tv) + be, 0.f);
                po[0][ni] += w0f*y; po[1][ni] += w1f*y; po[2][ni] += w2f*y;
            }
        }
    }
    #pragma unroll
    for (int o=0;o<3;o++)
      #pragma unroll
      for (int ni=0;ni<4;ni++) {
        float pv = po[o][ni];
        pv += __shfl_xor(pv, 16, 64);
        pv += __shfl_xor(pv, 32, 64);
        if (quad == o) {
            int h = y0 + wid*4 + ni, w = x0 + n16;
            outp[((size_t)b*3 + o)*HWSZ + h*256 + w] = pv + s_bf[o];
        }
      }
}

// ---------------------------------------------------------------------------
// msgterm / idx / dft / delta
// ---------------------------------------------------------------------------
__global__ __launch_bounds__(256) void msgterm_k(const float* __restrict__ msg,
                                                 const float* __restrict__ wa,
                                                 float* __restrict__ Tbuf)
{
    __shared__ float red[256];
    int b = blockIdx.x, o = blockIdx.y, l = threadIdx.x;
    float m = msg[b*NL + l];
    float wv[9];
    #pragma unroll
    for (int t=0;t<9;t++) wv[t] = wa[((size_t)o*323 + l)*9 + t] * m;
    float comp[9];
    comp[0] = wv[0]+wv[1]+wv[2]+wv[3]+wv[4]+wv[5]+wv[6]+wv[7]+wv[8];
    comp[1] = wv[0]+wv[1]+wv[2];
    comp[2] = wv[6]+wv[7]+wv[8];
    comp[3] = wv[0]+wv[3]+wv[6];
    comp[4] = wv[2]+wv[5]+wv[8];
    comp[5] = wv[0]; comp[6]=wv[2]; comp[7]=wv[6]; comp[8]=wv[8];
    for (int cpi=0;cpi<9;cpi++){
        red[l] = comp[cpi];
        __syncthreads();
        for (int s=128;s>0;s>>=1){ if (l<s) red[l]+=red[l+s]; __syncthreads(); }
        if (l==0) Tbuf[((size_t)b*CC+o)*9+cpi] = red[0];
        __syncthreads();
    }
}

__global__ void build_idx_k(int* __restrict__ idx)
{
    if (threadIdx.x==0 && blockIdx.x==0) {
        int n=0;
        for (int i=-10;i<=10;i++)
            for (int j=-10;j<=10;j++) {
                if (n>=NL) return;
                if (i*i+j*j<=100) { idx[2*n]=128+i; idx[2*n+1]=128+j; n++; }
            }
    }
}

__global__ __launch_bounds__(256) void dft_k(const float* __restrict__ plane,
                                             const float* __restrict__ msg,
                                             const int* __restrict__ idx,
                                             float* __restrict__ D)
{
    __shared__ float twc[256], tws[256], red[256];
    int k = blockIdx.x, b = blockIdx.y, w = threadIdx.x;
    float sv, cv;
    __sincosf(6.283185307179586f * (float)w / 256.0f, &sv, &cv);
    twc[w]=cv; tws[w]=sv;
    __syncthreads();
    int yk = idx[2*k], xk = idx[2*k+1];
    const float* pb = &plane[(size_t)b*HWSZ];
    int m = (xk*w) & 255;
    float fr=0.f, fi=0.f;
    for (int h=0; h<256; h++) {
        float xv = pb[h*256 + w];
        fr += xv*twc[m];
        fi -= xv*tws[m];
        m = (m + yk) & 255;
    }
    red[w]=fr; __syncthreads();
    for (int s=128;s>0;s>>=1){ if(w<s) red[w]+=red[w+s]; __syncthreads(); }
    float FR = red[0]; __syncthreads();
    red[w]=fi; __syncthreads();
    for (int s=128;s>0;s>>=1){ if(w<s) red[w]+=red[w+s]; __syncthreads(); }
    if (w==0) {
        float FI = red[0];
        float mv = msg[b*NL + k];
        D[((size_t)b*NL + k)*2 + 0] = mv - FR;
        D[((size_t)b*NL + k)*2 + 1] = mv - FI;
    }
}

__global__ __launch_bounds__(256) void deltaplane_k(const int* __restrict__ idx,
                                                    const float* __restrict__ D,
                                                    float* __restrict__ dplane)
{
    __shared__ float twc[256], tws[256], dr[256], di[256];
    __shared__ int iy[256], ix[256];
    int h = blockIdx.x, b = blockIdx.y, w = threadIdx.x;
    float sv, cv;
    __sincosf(6.283185307179586f * (float)w / 256.0f, &sv, &cv);
    twc[w]=cv; tws[w]=sv;
    dr[w] = D[((size_t)b*NL + w)*2+0];
    di[w] = D[((size_t)b*NL + w)*2+1];
    iy[w] = idx[2*w]; ix[w] = idx[2*w+1];
    __syncthreads();
    float acc = 0.f;
    for (int k=0;k<NL;k++) {
        int m = (iy[k]*h + ix[k]*w) & 255;
        acc += dr[k]*twc[m] - di[k]*tws[m];
    }
    dplane[(size_t)b*HWSZ + h*256 + w] = acc * (1.0f/65536.0f);
}

// ---------------------------------------------------------------------------
extern "C" void kernel_launch(void* const* d_in, const int* in_sizes, int n_in,
                              void* d_out, int out_size, void* d_ws, size_t ws_size,
                              hipStream_t stream)
{
    const float* image = (const float*)d_in[0];
    const float* msg   = (const float*)d_in[1];
    const float* w0    = (const float*)d_in[2];
    const float* b0    = (const float*)d_in[3];
    const float* g0    = (const float*)d_in[4];
    const float* be0   = (const float*)d_in[5];
    const float* m0    = (const float*)d_in[6];
    const float* v0    = (const float*)d_in[7];
    const float* wk    = (const float*)d_in[8];
    const float* bk    = (const float*)d_in[9];
    const float* gk    = (const float*)d_in[10];
    const float* bek   = (const float*)d_in[11];
    const float* mk    = (const float*)d_in[12];
    const float* vk    = (const float*)d_in[13];
    const float* wa    = (const float*)d_in[14];
    const float* ba    = (const float*)d_in[15];
    const float* ga    = (const float*)d_in[16];
    const float* bea   = (const float*)d_in[17];
    const float* ma    = (const float*)d_in[18];
    const float* va    = (const float*)d_in[19];
    const float* wf    = (const float*)d_in[20];
    const float* bfv   = (const float*)d_in[21];
    float* out = (float*)d_out;

    char* base = (char*)d_ws;
    int*    idx    = (int*)base;                       // 2 KB
    float*  Dbuf   = (float*)(base + (4<<10));         // 32 KB
    float*  Tbuf   = (float*)(base + (64<<10));        // 36 KB
    ushort* wkb2   = (ushort*)(base + (128<<10));      // 216 KB
    ushort* wab2   = (ushort*)(base + (512<<10));      // 108 KB
    float*  plane  = (float*)(base + ((size_t)1<<20)); // 4 MB
    float*  dplane = (float*)(base + ((size_t)5<<20)); // 4 MB
    ushort* bufA   = (ushort*)(base + ((size_t)16<<20));

    const size_t perB = (size_t)HWSZ*64*2*2;  // 16 MiB: both bf16 buffers / batch
    int chunk = 1;
    for (int c = NB; c >= 1; c >>= 1)
        if (((size_t)16<<20) + (size_t)c*perB <= ws_size) { chunk = c; break; }
    ushort* bufB = bufA + (size_t)chunk*HWSZ*64;

    build_idx_k<<<1,64,0,stream>>>(idx);
    msgterm_k<<<dim3(NB,CC),256,0,stream>>>(msg, wa, Tbuf);
    int prep_n = (3*9*64*64 + 9*64*96 + 255)/256;
    prep_w_k<<<prep_n,256,0,stream>>>(wk, wa, wkb2, wab2);

    const size_t WL = (size_t)9*64*64;  // one layer of wkb2

    for (int cs = 0; cs < NB; cs += chunk) {
        dim3 g(16,16,chunk);
        const float* img_c = image + (size_t)cs*3*HWSZ;

        conv0_k<<<g,256,0,stream>>>(img_c, w0, b0, g0, be0, m0, v0, bufA);
        convm_k<<<g,256,0,stream>>>(bufA, wkb2 + 0*WL, bufB,
            gk+0*CC, bek+0*CC, mk+0*CC, vk+0*CC, bk+0*CC, nullptr);
        convm_k<<<g,256,0,stream>>>(bufB, wkb2 + 1*WL, bufA,
            gk+1*CC, bek+1*CC, mk+1*CC, vk+1*CC, bk+1*CC, nullptr);
        convm_k<<<g,256,0,stream>>>(bufA, wkb2 + 2*WL, bufB,
            gk+2*CC, bek+2*CC, mk+2*CC, vk+2*CC, bk+2*CC, plane);

        dft_k<<<dim3(NL,chunk),256,0,stream>>>(plane, msg + (size_t)cs*NL, idx, Dbuf);
        deltaplane_k<<<dim3(HH,chunk),256,0,stream>>>(idx, Dbuf, dplane);

        conva_k<<<g,256,0,stream>>>(bufB, img_c, dplane, wab2,
            ga, bea, ma, va, ba, Tbuf + (size_t)cs*CC*9, wf, bfv,
            out + (size_t)cs*3*HWSZ);
    }
}